// Round 1
// baseline (237.613 us; speedup 1.0000x reference)
//
#include <hip/hip_runtime.h>

#define EPSL 1e-9f
// B=8192, A=26, D=93  ->  N = 19,808,256 floats per tensor (divisible by 4)
#define N_TOTAL 19808256
#define N4 (N_TOTAL / 4)

__global__ __launch_bounds__(256) void laneline_reduce_kernel(
    const float* __restrict__ pred,
    const float* __restrict__ gt,
    float* __restrict__ ws)
{
    float s0 = 0.f;  // vis BCE accumulator (positive inner sum)
    float s1 = 0.f;  // class BCE accumulator
    float s2 = 0.f;  // anchor L1 accumulator

    const int stride = gridDim.x * blockDim.x;
    for (int j = blockIdx.x * blockDim.x + threadIdx.x; j < N4; j += stride) {
        const int base = 4 * j;
        const float4 p4 = reinterpret_cast<const float4*>(pred)[j];
        const float4 g4 = reinterpret_cast<const float4*>(gt)[j];
        const float pv[4] = {p4.x, p4.y, p4.z, p4.w};
        const float gv[4] = {g4.x, g4.y, g4.z, g4.w};
#pragma unroll
        for (int k = 0; k < 4; ++k) {
            const int idx = base + k;
            const int grp = idx / 31;           // magic-mul division by constant
            const int d   = idx - grp * 31;
            const float p = pv[k];
            const float g = gv[k];
            if (d < 20) {
                // anchor: |gt_class * gt_vis[d%10] * (pred - gt)|
                const int vd = (d >= 10) ? (d - 10) : d;
                const float gvis = gt[grp * 31 + 20 + vd];   // L1-hot
                const float gcls = gt[grp * 31 + 30];        // L1-hot
                s2 += fabsf(gcls * gvis * (p - g));
            } else if (d < 30) {
                // visibility BCE (note +EPS inside (1 - gt_vis + EPS))
                s0 += g * logf(p + EPSL) + (1.0f - g + EPSL) * logf(1.0f - p + EPSL);
            } else {
                // class BCE (no +EPS on (1 - gt_class))
                s1 += g * logf(p + EPSL) + (1.0f - g) * logf(1.0f - p + EPSL);
            }
        }
    }

    // wave(64) shuffle reduction
#pragma unroll
    for (int off = 32; off > 0; off >>= 1) {
        s0 += __shfl_down(s0, off, 64);
        s1 += __shfl_down(s1, off, 64);
        s2 += __shfl_down(s2, off, 64);
    }

    __shared__ float sm0[4], sm1[4], sm2[4];
    const int lane = threadIdx.x & 63;
    const int wid  = threadIdx.x >> 6;
    if (lane == 0) { sm0[wid] = s0; sm1[wid] = s1; sm2[wid] = s2; }
    __syncthreads();
    if (threadIdx.x == 0) {
        const float t0 = sm0[0] + sm0[1] + sm0[2] + sm0[3];
        const float t1 = sm1[0] + sm1[1] + sm1[2] + sm1[3];
        const float t2 = sm2[0] + sm2[1] + sm2[2] + sm2[3];
        atomicAdd(&ws[0], t0);
        atomicAdd(&ws[1], t1);
        atomicAdd(&ws[2], t2);
    }
}

__global__ void laneline_finalize_kernel(const float* __restrict__ ws,
                                         float* __restrict__ out)
{
    if (threadIdx.x == 0 && blockIdx.x == 0) {
        const float l0 = -ws[0] * 0.1f;   // / NUM_Y_STEPS, negated
        const float l1 = -ws[1];
        const float l2 =  ws[2];
        out[0] = l0 + l1 + l2;
        out[1] = l0;
        out[2] = l1;
        out[3] = l2;
    }
}

extern "C" void kernel_launch(void* const* d_in, const int* in_sizes, int n_in,
                              void* d_out, int out_size, void* d_ws, size_t ws_size,
                              hipStream_t stream)
{
    const float* pred = (const float*)d_in[0];
    const float* gt   = (const float*)d_in[1];
    // d_in[2..5] (hcam/pitch) are unused by the reference computation.
    float* ws  = (float*)d_ws;
    float* out = (float*)d_out;

    hipMemsetAsync(ws, 0, 3 * sizeof(float), stream);  // ws is 0xAA-poisoned each call

    laneline_reduce_kernel<<<1024, 256, 0, stream>>>(pred, gt, ws);
    laneline_finalize_kernel<<<1, 64, 0, stream>>>(ws, out);
}